// Round 15
// baseline (1636.907 us; speedup 1.0000x reference)
//
#include <hip/hip_runtime.h>

#define NGRAPH 512
#define NNODE  128
#define NEDGE  512
#define EMB    300
#define NLAYER 5
#define FA     9
#define FB     3
#define VV     64
#define KPAD   136   // padded K stride (bf16 elems) for A / xT tiles

typedef __bf16 bf16x8 __attribute__((ext_vector_type(8)));
typedef __bf16 bf16x4 __attribute__((ext_vector_type(4)));
typedef float  f32x4  __attribute__((ext_vector_type(4)));

__device__ __forceinline__ void gload_lds16(const void* gptr, void* lptr) {
    __builtin_amdgcn_global_load_lds(
        (const __attribute__((address_space(1))) void*)gptr,
        (__attribute__((address_space(3))) void*)lptr, 16, 0, 0);
}

// ---------------------------------------------------------------------------
// Kernel 0: weight prep — transpose w1/w2 to bf16 [N][K] (padded, zeros).
// ---------------------------------------------------------------------------
__global__ __launch_bounds__(256)
void prep_w_kernel(const float* __restrict__ w1, const float* __restrict__ w2,
                   __bf16* __restrict__ w1t, __bf16* __restrict__ w2t)
{
    const int i = blockIdx.x * 256 + threadIdx.x;
    const int T1 = NLAYER * 640 * 320;
    const int T2 = NLAYER * 320 * 640;
    if (i < T1) {
        const int l = i / (640 * 320);
        const int r = i - l * 640 * 320;
        const int n = r / 320, k = r - n * 320;
        float v = (n < 600 && k < 300) ? w1[((size_t)l * 300 + k) * 600 + n] : 0.f;
        w1t[i] = (__bf16)v;
    } else if (i < T1 + T2) {
        const int j = i - T1;
        const int l = j / (320 * 640);
        const int r = j - l * 320 * 640;
        const int n = r / 640, k = r - n * 640;
        float v = (n < 300 && k < 600) ? w2[((size_t)l * 600 + k) * 300 + n] : 0.f;
        w2t[j] = (__bf16)v;
    }
}

// ---------------------------------------------------------------------------
// Kernel 0b: one-shot CSR precompute (unchanged).
// ---------------------------------------------------------------------------
__global__ __launch_bounds__(128)
void csr_kernel(const int* __restrict__ edge_index,
                const int* __restrict__ edge_attr,
                int* __restrict__ epk_sorted,     // [G][512]
                int* __restrict__ off_g)          // [G][129]
{
    __shared__ int epk_s[NEDGE];
    __shared__ int cnt[128];
    __shared__ int off_[129];

    const int tid = threadIdx.x;
    const int g   = blockIdx.x;

    cnt[tid] = 0;
    __syncthreads();
    for (int e = tid; e < NEDGE; e += 128) {
        const int s_ = edge_index[(g * 2 + 0) * NEDGE + e];
        const int d_ = edge_index[(g * 2 + 1) * NEDGE + e];
        const int base = (g * NEDGE + e) * 3;
        epk_s[e] = s_ | (d_ << 7) | (edge_attr[base + 0] << 14)
                 | (edge_attr[base + 1] << 20) | (edge_attr[base + 2] << 26);
        atomicAdd(&cnt[d_], 1);
    }
    __syncthreads();
    if (tid < 64) {
        const int a = cnt[tid];
        const int b = cnt[64 + tid];
        int ia = a;
        #pragma unroll
        for (int o = 1; o < 64; o <<= 1) {
            int t = __shfl_up(ia, o, 64);
            if (tid >= o) ia += t;
        }
        const int totA = __shfl(ia, 63, 64);
        int ib = b;
        #pragma unroll
        for (int o = 1; o < 64; o <<= 1) {
            int t = __shfl_up(ib, o, 64);
            if (tid >= o) ib += t;
        }
        off_[tid]      = ia - a;
        off_[64 + tid] = totA + ib - b;
        if (tid == 63) off_[128] = totA + ib;
    }
    __syncthreads();
    off_g[g * 129 + tid] = off_[tid];
    if (tid == 0) off_g[g * 129 + 128] = off_[128];
    int pos = off_[tid];
    for (int e = 0; e < NEDGE; ++e) {
        const int p = epk_s[e];
        if (((p >> 7) & 127) == tid) epk_sorted[(g << 9) + pos++] = p;
    }
}

// ---------------------------------------------------------------------------
// Kernel 1a: adjacency build (unchanged from round 14).
// ---------------------------------------------------------------------------
__global__ __launch_bounds__(512)
void adj_kernel(const int* __restrict__ edge_index,
                const int* __restrict__ edge_attr,
                const float* __restrict__ bond_tab_root,
                const float* __restrict__ edge_lin_w,
                const float* __restrict__ edge_lin_b,
                __bf16* __restrict__ Ahi_g, __bf16* __restrict__ Alo_g)
{
    __shared__ float A[128 * 129];
    __shared__ float ew_s[NEDGE];
    __shared__ int   es[NEDGE];
    __shared__ float rinv[128];
    __shared__ float cinv[128];

    const int tid = threadIdx.x;
    const int g   = blockIdx.x;
    int* Ai = (int*)A;

    for (int e = tid; e < NEDGE; e += 512) {
        int r = edge_index[(g * 2 + 0) * NEDGE + e];
        int c = edge_index[(g * 2 + 1) * NEDGE + e];
        es[e] = r | (c << 8);
    }
    for (int i = tid; i < 128 * 129; i += 512) Ai[i] = -1;
    __syncthreads();

    // edge weights: 8 lanes per edge, 8 edges per wave-iteration
    {
        const int wave = tid >> 6, lane = tid & 63;
        const int sub = lane >> 3, sl = lane & 7;
        const float elb = edge_lin_b[0];
        #pragma unroll 2
        for (int it = 0; it < 8; ++it) {
            const int e = wave * 64 + it * 8 + sub;
            const int base = (g * NEDGE + e) * 3;
            const int a0 = edge_attr[base + 0];
            const int a1 = edge_attr[base + 1];
            const int a2 = edge_attr[base + 2];
            const float* t0 = bond_tab_root + (0 * VV + a0) * EMB;
            const float* t1 = bond_tab_root + (1 * VV + a1) * EMB;
            const float* t2 = bond_tab_root + (2 * VV + a2) * EMB;
            float acc = 0.f;
            for (int d = sl; d < EMB; d += 8)
                acc += (t0[d] + t1[d] + t2[d]) * edge_lin_w[d];
            acc += __shfl_xor(acc, 4, 64);
            acc += __shfl_xor(acc, 2, 64);
            acc += __shfl_xor(acc, 1, 64);
            if (sl == 0) ew_s[e] = 1.f / (1.f + expf(-(acc + elb)));
        }
    }
    for (int e = tid; e < NEDGE; e += 512) {
        int r = es[e] & 255, c = es[e] >> 8;
        atomicMax(&Ai[r * 129 + c], e);
        atomicMax(&Ai[c * 129 + r], 512 + e);
    }
    __syncthreads();
    for (int i = tid; i < 128 * 129; i += 512) {
        int p = Ai[i];
        A[i] = (p < 0) ? 0.f : ew_s[p & 511];
    }
    __syncthreads();
    if (tid < 128) A[tid * 129 + tid] += 1.f;
    __syncthreads();
    if (tid < 128) {
        float rs = 0.f, cs = 0.f;
        for (int j = 0; j < 128; ++j) { rs += A[tid * 129 + j]; cs += A[j * 129 + tid]; }
        rinv[tid] = 1.f / sqrtf(rs);
        cinv[tid] = 1.f / sqrtf(cs);
    }
    __syncthreads();
    for (int i = tid; i < 128 * KPAD; i += 512) {
        const int m = i / KPAD, k = i - m * KPAD;
        float v = (k < 128) ? A[m * 129 + k] * cinv[m] * rinv[k] : 0.f;
        __bf16 hi = (__bf16)v;
        Ahi_g[(size_t)g * 128 * KPAD + i] = hi;
        Alo_g[(size_t)g * 128 * KPAD + i] = (__bf16)(v - (float)hi);
    }
}

// ---------------------------------------------------------------------------
// Kernel 1b: diffusion via MFMA (unchanged from round 14).
// ---------------------------------------------------------------------------
__global__ __launch_bounds__(1024)
void diffuse_mm_kernel(const int* __restrict__ order_p,
                       const int* __restrict__ x_atom,
                       const float* __restrict__ atom_tab,
                       const __bf16* __restrict__ Ahi_g,
                       const __bf16* __restrict__ Alo_g,
                       __bf16* __restrict__ hb)
{
    __shared__ __bf16 Ahi[128 * KPAD];
    __shared__ __bf16 Alo[128 * KPAD];
    __shared__ __bf16 xt[2 * 64 * KPAD];
    __shared__ int    xat[128 * FA];

    const int tid  = threadIdx.x;
    const int g    = blockIdx.x;
    const int lane = tid & 63;
    const int wid  = tid >> 6;
    const int wm   = (wid >> 2) * 32;
    const int wn   = (wid & 3) * 16;
    const int lr   = lane & 15;
    const int q4   = (lane >> 4) * 4;
    const int kc   = (lane >> 4) * 8;

    for (int idx = tid; idx < 128 * KPAD / 8; idx += 1024) {
        gload_lds16(Ahi_g + (size_t)g * 128 * KPAD + idx * 8, (char*)Ahi + idx * 16);
        gload_lds16(Alo_g + (size_t)g * 128 * KPAD + idx * 8, (char*)Alo + idx * 16);
    }
    for (int i = tid; i < 128 * FA; i += 1024) xat[i] = x_atom[g * 128 * FA + i];
    __syncthreads();

    const int   ord    = order_p[0];
    const float yscale = 1.f / (float)(ord + 1);
    const int   n_     = wn + lr;

    for (int cb = 0; cb < 5; ++cb) {
        const int dbase = cb * 64;
        const int d     = dbase + n_;

        float yacc[2][4];
        #pragma unroll
        for (int mi = 0; mi < 2; ++mi) {
            #pragma unroll
            for (int r = 0; r < 4; ++r) {
                const int m_ = wm + mi * 16 + q4 + r;
                float v = 0.f;
                if (d < EMB) {
                    #pragma unroll
                    for (int f = 0; f < FA; ++f)
                        v += atom_tab[(size_t)((f << 6) + xat[m_ * FA + f]) * EMB + d];
                    v *= 0.8f;
                }
                yacc[mi][r] = v;
                xt[0 * 64 * KPAD + n_ * KPAD + m_] = (__bf16)v;
            }
        }
        __syncthreads();

        int curbuf = 0;
        for (int o = 0; o < ord; ++o) {
            const __bf16* xh = xt + curbuf * 64 * KPAD;
            f32x4 racc[2];
            racc[0] = (f32x4){0.f, 0.f, 0.f, 0.f};
            racc[1] = (f32x4){0.f, 0.f, 0.f, 0.f};

            #pragma unroll
            for (int ks = 0; ks < 4; ++ks) {
                const int k0 = ks * 32 + kc;
                bf16x8 ah[2], al[2], bh;
                #pragma unroll
                for (int mi = 0; mi < 2; ++mi) {
                    ah[mi] = *(const bf16x8*)&Ahi[(wm + mi * 16 + lr) * KPAD + k0];
                    al[mi] = *(const bf16x8*)&Alo[(wm + mi * 16 + lr) * KPAD + k0];
                }
                bh = *(const bf16x8*)&xh[(wn + lr) * KPAD + k0];
                #pragma unroll
                for (int mi = 0; mi < 2; ++mi) {
                    racc[mi] = __builtin_amdgcn_mfma_f32_16x16x32_bf16(
                        ah[mi], bh, racc[mi], 0, 0, 0);
                    racc[mi] = __builtin_amdgcn_mfma_f32_16x16x32_bf16(
                        al[mi], bh, racc[mi], 0, 0, 0);
                }
            }

            __bf16* nh = xt + (curbuf ^ 1) * 64 * KPAD;
            #pragma unroll
            for (int mi = 0; mi < 2; ++mi) {
                const int mbase = wm + mi * 16 + q4;
                bf16x4 hv;
                #pragma unroll
                for (int r = 0; r < 4; ++r) {
                    const float v = racc[mi][r];
                    yacc[mi][r] += v;
                    hv[r] = (__bf16)v;
                }
                *(bf16x4*)&nh[n_ * KPAD + mbase] = hv;
            }
            __syncthreads();
            curbuf ^= 1;
        }

        #pragma unroll
        for (int mi = 0; mi < 2; ++mi) {
            #pragma unroll
            for (int r = 0; r < 4; ++r) {
                const int m_ = wm + mi * 16 + q4 + r;
                const float v = (d < EMB) ? yacc[mi][r] * yscale : 0.f;
                hb[(size_t)(g * 128 + m_) * 320 + d] = (__bf16)v;
            }
        }
    }
}

// ---------------------------------------------------------------------------
// Kernel 2: GIN aggregation, CSR-precomputed gather (unchanged).
// ---------------------------------------------------------------------------
__global__ __launch_bounds__(1024)
void agg_kernel(const __bf16* __restrict__ hb,
                const int* __restrict__ epk_sorted,
                const int* __restrict__ off_g,
                const float* __restrict__ bond_tabs,
                const float* __restrict__ eps_all,
                const int l,
                __bf16* __restrict__ zb)
{
    __shared__ __bf16 hs[128 * 160];

    const int tid  = threadIdx.x;
    const int g    = blockIdx.x >> 1;
    const int coff = (blockIdx.x & 1) * 160;
    const int wave = tid >> 6, lane = tid & 63;
    const float epl = 1.f + eps_all[l];
    const float* bt = bond_tabs + (size_t)l * FB * VV * EMB;

    for (int idx = tid; idx < 128 * 20; idx += 1024) {
        const int r = idx / 20, c = idx - r * 20;
        *(bf16x8*)&hs[r * 160 + c * 8] =
            *(const bf16x8*)&hb[(size_t)(g * 128 + r) * 320 + coff + c * 8];
    }
    __syncthreads();

    const int d0 = lane, d1 = lane + 64, d2 = lane + 128;
    const bool r0 = (coff + d0) < EMB;
    const bool r1 = (coff + d1) < EMB;
    const bool r2 = (d2 < 160) && ((coff + d2) < EMB);

    const int* offg = off_g + g * 129;
    const int* epkg = epk_sorted + (g << 9);

    for (int n = wave; n < 128; n += 16) {
        float a0 = r0 ? epl * (float)hs[n * 160 + d0] : 0.f;
        float a1 = r1 ? epl * (float)hs[n * 160 + d1] : 0.f;
        float a2 = r2 ? epl * (float)hs[n * 160 + d2] : 0.f;
        const int eBeg = offg[n], eEnd = offg[n + 1];
        for (int ee = eBeg; ee < eEnd; ++ee) {
            const int p   = epkg[ee];
            const int src = p & 127;
            const float* t0 = bt + ((p >> 14) & 63) * EMB + coff;
            const float* t1 = bt + (64  + ((p >> 20) & 63)) * EMB + coff;
            const float* t2 = bt + (128 + ((p >> 26) & 63)) * EMB + coff;
            if (r0) a0 += fmaxf((float)hs[src * 160 + d0] + t0[d0] + t1[d0] + t2[d0], 0.f);
            if (r1) a1 += fmaxf((float)hs[src * 160 + d1] + t0[d1] + t1[d1] + t2[d1], 0.f);
            if (r2) a2 += fmaxf((float)hs[src * 160 + d2] + t0[d2] + t1[d2] + t2[d2], 0.f);
        }
        __bf16* zrow = zb + (size_t)(g * 128 + n) * 320 + coff;
        zrow[d0] = (__bf16)a0;
        zrow[d1] = (__bf16)a1;
        if (d2 < 160) zrow[d2] = (__bf16)a2;
    }
}

// ---------------------------------------------------------------------------
// Kernel 3: SKINNY-K bf16 MFMA GEMM, barrier-free K-loop.
// B strip (64 N-rows x 320 k) staged ONCE per chunk into padded LDS
// (stride 328 kills the 640B-stride bank pathology); A-fragments loaded
// global->VGPR (no LDS, no barriers in the K-loop). NCH = # of 320-k
// chunks (1 for gemm1, 2 for gemm2; one barrier between chunks).
// Epilogue: LDS-staged coalesced stores (reuses the Bs buffer).
// ---------------------------------------------------------------------------
template <int NCH, int CBF16, int RELU>
__global__ __launch_bounds__(256)
void gemm_skinny(const __bf16* __restrict__ A, const int lda,
                 const int nBlkN, const __bf16* __restrict__ B,
                 void* __restrict__ Cv, const int ldc, const int Nreal,
                 const float* __restrict__ bias, const float* __restrict__ gam,
                 const float* __restrict__ bet)
{
    __shared__ __align__(16) char smem_raw[64 * 328 * 2];   // 41,984 B

    const int tid  = threadIdx.x;
    const int nwg  = gridDim.x;
    const int hw   = blockIdx.x;
    const int lg   = (hw & 7) * (nwg >> 3) + (hw >> 3);   // XCD-chunk swizzle
    const int bn   = (lg % nBlkN) * 64;
    const int bm   = (lg / nBlkN) * 128;
    const int wid  = tid >> 6;
    const int lane = tid & 63;
    const int wm   = (wid >> 1) * 64;
    const int wn   = (wid & 1) * 32;
    const int lr   = lane & 15;
    const int kc   = (lane >> 4) * 8;
    const int q4   = (lane >> 4) * 4;
    const int KPg  = NCH * 320;          // global K stride

    unsigned short* Bs = (unsigned short*)smem_raw;   // [64][328]

    f32x4 acc[4][2];
    #pragma unroll
    for (int mi = 0; mi < 4; ++mi)
        #pragma unroll
        for (int ni = 0; ni < 2; ++ni) acc[mi][ni] = (f32x4){0.f, 0.f, 0.f, 0.f};

    #pragma unroll
    for (int ch = 0; ch < NCH; ++ch) {
        if (ch > 0) __syncthreads();     // previous chunk's reads done
        // stage B strip: 64 rows x 320 k, reg-staged into padded LDS
        #pragma unroll
        for (int q = 0; q < 10; ++q) {
            const int idx = q * 256 + tid;
            const int row = idx / 40, c8 = (idx - row * 40) * 8;
            bf16x8 v = *(const bf16x8*)&B[(size_t)(bn + row) * KPg + ch * 320 + c8];
            *(bf16x8*)&Bs[row * 328 + c8] = v;
        }
        __syncthreads();

        // barrier-free K loop: A-frags global->reg, B-frags from LDS
        const __bf16* Abase = A + (size_t)bm * lda + ch * 320;
        #pragma unroll
        for (int kt = 0; kt < 10; ++kt) {
            const int k0 = kt * 32 + kc;
            bf16x8 a[4], b[2];
            #pragma unroll
            for (int mi = 0; mi < 4; ++mi)
                a[mi] = *(const bf16x8*)&Abase[(size_t)(wm + mi * 16 + lr) * lda + k0];
            #pragma unroll
            for (int ni = 0; ni < 2; ++ni)
                b[ni] = *(const bf16x8*)&Bs[(wn + ni * 16 + lr) * 328 + k0];
            #pragma unroll
            for (int mi = 0; mi < 4; ++mi)
                #pragma unroll
                for (int ni = 0; ni < 2; ++ni)
                    acc[mi][ni] = __builtin_amdgcn_mfma_f32_16x16x32_bf16(
                        a[mi], b[ni], acc[mi][ni], 0, 0, 0);
        }
    }
    __syncthreads();   // all Bs reads done; reuse smem for epilogue

    // ---- staged coalesced epilogue ----
    float gv[2], bv[2], ev[2];
    #pragma unroll
    for (int ni = 0; ni < 2; ++ni) {
        const int n = bn + wn + ni * 16 + lr;
        const bool nv = (n < Nreal);
        gv[ni] = nv ? gam[n]  : 0.f;
        bv[ni] = nv ? bias[n] : 0.f;
        ev[ni] = nv ? bet[n]  : 0.f;
    }

    if (CBF16) {
        __bf16* Cb = (__bf16*)smem_raw;               // [64][72] padded
        #pragma unroll
        for (int half = 0; half < 2; ++half) {
            if ((wm >> 6) == half) {
                #pragma unroll
                for (int ni = 0; ni < 2; ++ni) {
                    const int nl = wn + ni * 16 + lr;
                    #pragma unroll
                    for (int mi = 0; mi < 4; ++mi) {
                        #pragma unroll
                        for (int r = 0; r < 4; ++r) {
                            float v = gv[ni] * (acc[mi][ni][r] + bv[ni]) + ev[ni];
                            if (RELU) v = fmaxf(v, 0.f);
                            Cb[(mi * 16 + q4 + r) * 72 + nl] = (__bf16)v;
                        }
                    }
                }
            }
            __syncthreads();
            #pragma unroll
            for (int q = 0; q < 2; ++q) {
                const int idx = q * 256 + tid;
                const int row = idx >> 3, c16 = (idx & 7) * 8;
                const size_t m = (size_t)bm + half * 64 + row;
                *(bf16x8*)&((__bf16*)Cv)[m * ldc + bn + c16] =
                    *(const bf16x8*)&Cb[row * 72 + c16];
            }
            __syncthreads();
        }
    } else {
        float* Cf = (float*)smem_raw;                 // [32][68] padded
        const int ncols = (Nreal - bn < 64) ? (Nreal - bn) : 64;
        const int nch = ncols >> 2;
        #pragma unroll
        for (int mq = 0; mq < 4; ++mq) {
            if ((wm >> 6) == (mq >> 1)) {
                const int mi0 = (mq & 1) * 2;
                #pragma unroll
                for (int ni = 0; ni < 2; ++ni) {
                    const int nl = wn + ni * 16 + lr;
                    #pragma unroll
                    for (int mi2 = 0; mi2 < 2; ++mi2) {
                        const int mi = mi0 + mi2;
                        #pragma unroll
                        for (int r = 0; r < 4; ++r) {
                            float v = gv[ni] * (acc[mi][ni][r] + bv[ni]) + ev[ni];
                            if (RELU) v = fmaxf(v, 0.f);
                            Cf[(mi2 * 16 + q4 + r) * 68 + nl] = v;
                        }
                    }
                }
            }
            __syncthreads();
            for (int idx = tid; idx < 32 * nch; idx += 256) {
                const int row = idx / nch, c4 = (idx - row * nch) * 4;
                const size_t m = (size_t)bm + mq * 32 + row;
                *(float4*)&((float*)Cv)[m * ldc + bn + c4] =
                    *(const float4*)&Cf[row * 68 + c4];
            }
            __syncthreads();
        }
    }
}

// ---------------------------------------------------------------------------
extern "C" void kernel_launch(void* const* d_in, const int* in_sizes, int n_in,
                              void* d_out, int out_size, void* d_ws, size_t ws_size,
                              hipStream_t stream)
{
    const int*   order_p       = (const int*)d_in[0];
    const int*   x_atom        = (const int*)d_in[1];
    const int*   edge_index    = (const int*)d_in[2];
    const int*   edge_attr     = (const int*)d_in[3];
    const float* atom_tab      = (const float*)d_in[4];
    const float* bond_tab_root = (const float*)d_in[5];
    const float* edge_lin_w    = (const float*)d_in[6];
    const float* edge_lin_b    = (const float*)d_in[7];
    const float* bond_tabs     = (const float*)d_in[8];
    const float* eps           = (const float*)d_in[9];
    const float* w1            = (const float*)d_in[10];
    const float* b1            = (const float*)d_in[11];
    const float* bn1g          = (const float*)d_in[12];
    const float* bn1b          = (const float*)d_in[13];
    const float* w2            = (const float*)d_in[14];
    const float* b2            = (const float*)d_in[15];
    const float* bng           = (const float*)d_in[16];
    const float* bnb           = (const float*)d_in[17];

    float*  h  = (float*)d_out;    // final fp32 output [65536][300]
    __bf16* hb = (__bf16*)d_out;   // inter-layer trunk bf16 [65536][320]

    char* ws = (char*)d_ws;
    __bf16* Ahi_g = (__bf16*)ws;                                  // (inside z1)
    __bf16* Alo_g = (__bf16*)(ws + 17825792);                     // (inside z1)
    __bf16* z1    = (__bf16*)ws;                                  // [65536][640]
    __bf16* w1t   = (__bf16*)(ws + 83886080);                     // [5][640][320]
    __bf16* w2t   = (__bf16*)(ws + 83886080 + 2048000);           // [5][320][640]
    __bf16* zb    = (__bf16*)(ws + 83886080 + 4096000);           // [65536][320]
    int*    epk_s = (int*)(ws + 83886080 + 4096000 + 41943040);   // [512][512]
    int*    off_g = (int*)(ws + 83886080 + 4096000 + 41943040 + 1048576); // [512][129]

    prep_w_kernel<<<8000, 256, 0, stream>>>(w1, w2, w1t, w2t);

    csr_kernel<<<NGRAPH, 128, 0, stream>>>(edge_index, edge_attr, epk_s, off_g);

    adj_kernel<<<NGRAPH, 512, 0, stream>>>(edge_index, edge_attr, bond_tab_root,
                                           edge_lin_w, edge_lin_b, Ahi_g, Alo_g);

    diffuse_mm_kernel<<<NGRAPH, 1024, 0, stream>>>(order_p, x_atom, atom_tab,
                                                   Ahi_g, Alo_g, hb);

    for (int l = 0; l < NLAYER; ++l) {
        agg_kernel<<<NGRAPH * 2, 1024, 0, stream>>>(
            hb, epk_s, off_g, bond_tabs, eps, l, zb);

        // gemm1: z1 = relu(bn1(zb @ w1 + b1)); K=320 (1 chunk)
        gemm_skinny<1, 1, 1><<<5120, 256, 0, stream>>>(
            zb, 320, 10, w1t + (size_t)l * 640 * 320,
            z1, 640, 600, b1 + l * 600, bn1g + l * 600, bn1b + l * 600);

        // gemm2: trunk = bn(z1 @ w2 + b2); K=640 (2 chunks)
        if (l < NLAYER - 1) {
            gemm_skinny<2, 1, 1><<<2560, 256, 0, stream>>>(
                z1, 640, 5, w2t + (size_t)l * 320 * 640,
                hb, 320, 300, b2 + l * 300, bng + l * 300, bnb + l * 300);
        } else {
            gemm_skinny<2, 0, 0><<<2560, 256, 0, stream>>>(
                z1, 640, 5, w2t + (size_t)l * 320 * 640,
                h, EMB, 300, b2 + l * 300, bng + l * 300, bnb + l * 300);
        }
    }
}

// Round 16
// 1073.840 us; speedup vs baseline: 1.5243x; 1.5243x over previous
//
#include <hip/hip_runtime.h>

#define NGRAPH 512
#define NNODE  128
#define NEDGE  512
#define EMB    300
#define NLAYER 5
#define FA     9
#define FB     3
#define VV     64
#define KPAD   136   // padded K stride (bf16 elems) for A / xT tiles

typedef __bf16 bf16x8 __attribute__((ext_vector_type(8)));
typedef __bf16 bf16x4 __attribute__((ext_vector_type(4)));
typedef float  f32x4  __attribute__((ext_vector_type(4)));

__device__ __forceinline__ void gload_lds16(const void* gptr, void* lptr) {
    __builtin_amdgcn_global_load_lds(
        (const __attribute__((address_space(1))) void*)gptr,
        (__attribute__((address_space(3))) void*)lptr, 16, 0, 0);
}

// ---------------------------------------------------------------------------
// Kernel 0: weight prep — w1/w2 -> bf16 [N][K] (padded, zeros); bond_tabs
// -> bf16 btb[L][192][300] for the agg message path.
// ---------------------------------------------------------------------------
__global__ __launch_bounds__(256)
void prep_w_kernel(const float* __restrict__ w1, const float* __restrict__ w2,
                   const float* __restrict__ bond_tabs,
                   __bf16* __restrict__ w1t, __bf16* __restrict__ w2t,
                   __bf16* __restrict__ btb)
{
    const int i = blockIdx.x * 256 + threadIdx.x;
    const int T1 = NLAYER * 640 * 320;
    const int T2 = NLAYER * 320 * 640;
    const int TB = NLAYER * FB * VV * EMB;   // 288,000
    if (i < T1) {
        const int l = i / (640 * 320);
        const int r = i - l * 640 * 320;
        const int n = r / 320, k = r - n * 320;
        float v = (n < 600 && k < 300) ? w1[((size_t)l * 300 + k) * 600 + n] : 0.f;
        w1t[i] = (__bf16)v;
    } else if (i < T1 + T2) {
        const int j = i - T1;
        const int l = j / (320 * 640);
        const int r = j - l * 320 * 640;
        const int n = r / 640, k = r - n * 640;
        float v = (n < 300 && k < 600) ? w2[((size_t)l * 600 + k) * 300 + n] : 0.f;
        w2t[j] = (__bf16)v;
    } else if (i < T1 + T2 + TB) {
        const int j = i - T1 - T2;
        btb[j] = (__bf16)bond_tabs[j];
    }
}

// ---------------------------------------------------------------------------
// Kernel 0b: one-shot CSR precompute (unchanged).
// ---------------------------------------------------------------------------
__global__ __launch_bounds__(128)
void csr_kernel(const int* __restrict__ edge_index,
                const int* __restrict__ edge_attr,
                int* __restrict__ epk_sorted,     // [G][512]
                int* __restrict__ off_g)          // [G][129]
{
    __shared__ int epk_s[NEDGE];
    __shared__ int cnt[128];
    __shared__ int off_[129];

    const int tid = threadIdx.x;
    const int g   = blockIdx.x;

    cnt[tid] = 0;
    __syncthreads();
    for (int e = tid; e < NEDGE; e += 128) {
        const int s_ = edge_index[(g * 2 + 0) * NEDGE + e];
        const int d_ = edge_index[(g * 2 + 1) * NEDGE + e];
        const int base = (g * NEDGE + e) * 3;
        epk_s[e] = s_ | (d_ << 7) | (edge_attr[base + 0] << 14)
                 | (edge_attr[base + 1] << 20) | (edge_attr[base + 2] << 26);
        atomicAdd(&cnt[d_], 1);
    }
    __syncthreads();
    if (tid < 64) {
        const int a = cnt[tid];
        const int b = cnt[64 + tid];
        int ia = a;
        #pragma unroll
        for (int o = 1; o < 64; o <<= 1) {
            int t = __shfl_up(ia, o, 64);
            if (tid >= o) ia += t;
        }
        const int totA = __shfl(ia, 63, 64);
        int ib = b;
        #pragma unroll
        for (int o = 1; o < 64; o <<= 1) {
            int t = __shfl_up(ib, o, 64);
            if (tid >= o) ib += t;
        }
        off_[tid]      = ia - a;
        off_[64 + tid] = totA + ib - b;
        if (tid == 63) off_[128] = totA + ib;
    }
    __syncthreads();
    off_g[g * 129 + tid] = off_[tid];
    if (tid == 0) off_g[g * 129 + 128] = off_[128];
    int pos = off_[tid];
    for (int e = 0; e < NEDGE; ++e) {
        const int p = epk_s[e];
        if (((p >> 7) & 127) == tid) epk_sorted[(g << 9) + pos++] = p;
    }
}

// ---------------------------------------------------------------------------
// Kernel 1a: adjacency build (unchanged from round 14).
// ---------------------------------------------------------------------------
__global__ __launch_bounds__(512)
void adj_kernel(const int* __restrict__ edge_index,
                const int* __restrict__ edge_attr,
                const float* __restrict__ bond_tab_root,
                const float* __restrict__ edge_lin_w,
                const float* __restrict__ edge_lin_b,
                __bf16* __restrict__ Ahi_g, __bf16* __restrict__ Alo_g)
{
    __shared__ float A[128 * 129];
    __shared__ float ew_s[NEDGE];
    __shared__ int   es[NEDGE];
    __shared__ float rinv[128];
    __shared__ float cinv[128];

    const int tid = threadIdx.x;
    const int g   = blockIdx.x;
    int* Ai = (int*)A;

    for (int e = tid; e < NEDGE; e += 512) {
        int r = edge_index[(g * 2 + 0) * NEDGE + e];
        int c = edge_index[(g * 2 + 1) * NEDGE + e];
        es[e] = r | (c << 8);
    }
    for (int i = tid; i < 128 * 129; i += 512) Ai[i] = -1;
    __syncthreads();

    // edge weights: 8 lanes per edge, 8 edges per wave-iteration
    {
        const int wave = tid >> 6, lane = tid & 63;
        const int sub = lane >> 3, sl = lane & 7;
        const float elb = edge_lin_b[0];
        #pragma unroll 2
        for (int it = 0; it < 8; ++it) {
            const int e = wave * 64 + it * 8 + sub;
            const int base = (g * NEDGE + e) * 3;
            const int a0 = edge_attr[base + 0];
            const int a1 = edge_attr[base + 1];
            const int a2 = edge_attr[base + 2];
            const float* t0 = bond_tab_root + (0 * VV + a0) * EMB;
            const float* t1 = bond_tab_root + (1 * VV + a1) * EMB;
            const float* t2 = bond_tab_root + (2 * VV + a2) * EMB;
            float acc = 0.f;
            for (int d = sl; d < EMB; d += 8)
                acc += (t0[d] + t1[d] + t2[d]) * edge_lin_w[d];
            acc += __shfl_xor(acc, 4, 64);
            acc += __shfl_xor(acc, 2, 64);
            acc += __shfl_xor(acc, 1, 64);
            if (sl == 0) ew_s[e] = 1.f / (1.f + expf(-(acc + elb)));
        }
    }
    for (int e = tid; e < NEDGE; e += 512) {
        int r = es[e] & 255, c = es[e] >> 8;
        atomicMax(&Ai[r * 129 + c], e);
        atomicMax(&Ai[c * 129 + r], 512 + e);
    }
    __syncthreads();
    for (int i = tid; i < 128 * 129; i += 512) {
        int p = Ai[i];
        A[i] = (p < 0) ? 0.f : ew_s[p & 511];
    }
    __syncthreads();
    if (tid < 128) A[tid * 129 + tid] += 1.f;
    __syncthreads();
    if (tid < 128) {
        float rs = 0.f, cs = 0.f;
        for (int j = 0; j < 128; ++j) { rs += A[tid * 129 + j]; cs += A[j * 129 + tid]; }
        rinv[tid] = 1.f / sqrtf(rs);
        cinv[tid] = 1.f / sqrtf(cs);
    }
    __syncthreads();
    for (int i = tid; i < 128 * KPAD; i += 512) {
        const int m = i / KPAD, k = i - m * KPAD;
        float v = (k < 128) ? A[m * 129 + k] * cinv[m] * rinv[k] : 0.f;
        __bf16 hi = (__bf16)v;
        Ahi_g[(size_t)g * 128 * KPAD + i] = hi;
        Alo_g[(size_t)g * 128 * KPAD + i] = (__bf16)(v - (float)hi);
    }
}

// ---------------------------------------------------------------------------
// Kernel 1b: diffusion via MFMA (unchanged from round 14).
// ---------------------------------------------------------------------------
__global__ __launch_bounds__(1024)
void diffuse_mm_kernel(const int* __restrict__ order_p,
                       const int* __restrict__ x_atom,
                       const float* __restrict__ atom_tab,
                       const __bf16* __restrict__ Ahi_g,
                       const __bf16* __restrict__ Alo_g,
                       __bf16* __restrict__ hb)
{
    __shared__ __bf16 Ahi[128 * KPAD];
    __shared__ __bf16 Alo[128 * KPAD];
    __shared__ __bf16 xt[2 * 64 * KPAD];
    __shared__ int    xat[128 * FA];

    const int tid  = threadIdx.x;
    const int g    = blockIdx.x;
    const int lane = tid & 63;
    const int wid  = tid >> 6;
    const int wm   = (wid >> 2) * 32;
    const int wn   = (wid & 3) * 16;
    const int lr   = lane & 15;
    const int q4   = (lane >> 4) * 4;
    const int kc   = (lane >> 4) * 8;

    for (int idx = tid; idx < 128 * KPAD / 8; idx += 1024) {
        gload_lds16(Ahi_g + (size_t)g * 128 * KPAD + idx * 8, (char*)Ahi + idx * 16);
        gload_lds16(Alo_g + (size_t)g * 128 * KPAD + idx * 8, (char*)Alo + idx * 16);
    }
    for (int i = tid; i < 128 * FA; i += 1024) xat[i] = x_atom[g * 128 * FA + i];
    __syncthreads();

    const int   ord    = order_p[0];
    const float yscale = 1.f / (float)(ord + 1);
    const int   n_     = wn + lr;

    for (int cb = 0; cb < 5; ++cb) {
        const int dbase = cb * 64;
        const int d     = dbase + n_;

        float yacc[2][4];
        #pragma unroll
        for (int mi = 0; mi < 2; ++mi) {
            #pragma unroll
            for (int r = 0; r < 4; ++r) {
                const int m_ = wm + mi * 16 + q4 + r;
                float v = 0.f;
                if (d < EMB) {
                    #pragma unroll
                    for (int f = 0; f < FA; ++f)
                        v += atom_tab[(size_t)((f << 6) + xat[m_ * FA + f]) * EMB + d];
                    v *= 0.8f;
                }
                yacc[mi][r] = v;
                xt[0 * 64 * KPAD + n_ * KPAD + m_] = (__bf16)v;
            }
        }
        __syncthreads();

        int curbuf = 0;
        for (int o = 0; o < ord; ++o) {
            const __bf16* xh = xt + curbuf * 64 * KPAD;
            f32x4 racc[2];
            racc[0] = (f32x4){0.f, 0.f, 0.f, 0.f};
            racc[1] = (f32x4){0.f, 0.f, 0.f, 0.f};

            #pragma unroll
            for (int ks = 0; ks < 4; ++ks) {
                const int k0 = ks * 32 + kc;
                bf16x8 ah[2], al[2], bh;
                #pragma unroll
                for (int mi = 0; mi < 2; ++mi) {
                    ah[mi] = *(const bf16x8*)&Ahi[(wm + mi * 16 + lr) * KPAD + k0];
                    al[mi] = *(const bf16x8*)&Alo[(wm + mi * 16 + lr) * KPAD + k0];
                }
                bh = *(const bf16x8*)&xh[(wn + lr) * KPAD + k0];
                #pragma unroll
                for (int mi = 0; mi < 2; ++mi) {
                    racc[mi] = __builtin_amdgcn_mfma_f32_16x16x32_bf16(
                        ah[mi], bh, racc[mi], 0, 0, 0);
                    racc[mi] = __builtin_amdgcn_mfma_f32_16x16x32_bf16(
                        al[mi], bh, racc[mi], 0, 0, 0);
                }
            }

            __bf16* nh = xt + (curbuf ^ 1) * 64 * KPAD;
            #pragma unroll
            for (int mi = 0; mi < 2; ++mi) {
                const int mbase = wm + mi * 16 + q4;
                bf16x4 hv;
                #pragma unroll
                for (int r = 0; r < 4; ++r) {
                    const float v = racc[mi][r];
                    yacc[mi][r] += v;
                    hv[r] = (__bf16)v;
                }
                *(bf16x4*)&nh[n_ * KPAD + mbase] = hv;
            }
            __syncthreads();
            curbuf ^= 1;
        }

        #pragma unroll
        for (int mi = 0; mi < 2; ++mi) {
            #pragma unroll
            for (int r = 0; r < 4; ++r) {
                const int m_ = wm + mi * 16 + q4 + r;
                const float v = (d < EMB) ? yacc[mi][r] * yscale : 0.f;
                hb[(size_t)(g * 128 + m_) * 320 + d] = (__bf16)v;
            }
        }
    }
}

// ---------------------------------------------------------------------------
// Kernel 2: GIN aggregation, CSR gather; bond tables read as bf16 (btb)
// to halve the dominant L2 stream. Otherwise identical to round 14.
// ---------------------------------------------------------------------------
__global__ __launch_bounds__(1024)
void agg_kernel(const __bf16* __restrict__ hb,
                const int* __restrict__ epk_sorted,
                const int* __restrict__ off_g,
                const __bf16* __restrict__ btb,
                const float* __restrict__ eps_all,
                const int l,
                __bf16* __restrict__ zb)
{
    __shared__ __bf16 hs[128 * 160];

    const int tid  = threadIdx.x;
    const int g    = blockIdx.x >> 1;
    const int coff = (blockIdx.x & 1) * 160;
    const int wave = tid >> 6, lane = tid & 63;
    const float epl = 1.f + eps_all[l];
    const __bf16* bt = btb + (size_t)l * FB * VV * EMB;

    for (int idx = tid; idx < 128 * 20; idx += 1024) {
        const int r = idx / 20, c = idx - r * 20;
        *(bf16x8*)&hs[r * 160 + c * 8] =
            *(const bf16x8*)&hb[(size_t)(g * 128 + r) * 320 + coff + c * 8];
    }
    __syncthreads();

    const int d0 = lane, d1 = lane + 64, d2 = lane + 128;
    const bool r0 = (coff + d0) < EMB;
    const bool r1 = (coff + d1) < EMB;
    const bool r2 = (d2 < 160) && ((coff + d2) < EMB);

    const int* offg = off_g + g * 129;
    const int* epkg = epk_sorted + (g << 9);

    for (int n = wave; n < 128; n += 16) {
        float a0 = r0 ? epl * (float)hs[n * 160 + d0] : 0.f;
        float a1 = r1 ? epl * (float)hs[n * 160 + d1] : 0.f;
        float a2 = r2 ? epl * (float)hs[n * 160 + d2] : 0.f;
        const int eBeg = offg[n], eEnd = offg[n + 1];
        for (int ee = eBeg; ee < eEnd; ++ee) {
            const int p   = epkg[ee];
            const int src = p & 127;
            const __bf16* t0 = bt + ((p >> 14) & 63) * EMB + coff;
            const __bf16* t1 = bt + (64  + ((p >> 20) & 63)) * EMB + coff;
            const __bf16* t2 = bt + (128 + ((p >> 26) & 63)) * EMB + coff;
            if (r0) a0 += fmaxf((float)hs[src * 160 + d0] + (float)t0[d0]
                                + (float)t1[d0] + (float)t2[d0], 0.f);
            if (r1) a1 += fmaxf((float)hs[src * 160 + d1] + (float)t0[d1]
                                + (float)t1[d1] + (float)t2[d1], 0.f);
            if (r2) a2 += fmaxf((float)hs[src * 160 + d2] + (float)t0[d2]
                                + (float)t1[d2] + (float)t2[d2], 0.f);
        }
        __bf16* zrow = zb + (size_t)(g * 128 + n) * 320 + coff;
        zrow[d0] = (__bf16)a0;
        zrow[d1] = (__bf16)a1;
        if (d2 < 160) zrow[d2] = (__bf16)a2;
    }
}

// ---------------------------------------------------------------------------
// Kernel 3: bf16 MFMA GEMM with XCD-chunk swizzle + LDS-staged coalesced
// epilogue (round-14 exact).
// ---------------------------------------------------------------------------
template <int CBF16, int RELU>
__global__ __launch_bounds__(256)
void gemm_mfma(const __bf16* __restrict__ A, const int lda,
               const int nT, const int nBlkN, const __bf16* __restrict__ B,
               void* __restrict__ Cv, const int ldc, const int Nreal,
               const float* __restrict__ bias, const float* __restrict__ gam,
               const float* __restrict__ bet)
{
    __shared__ __align__(16) char smem_raw[12288];
    unsigned short* As = (unsigned short*)smem_raw;            // 128x32 bf16 = 8 KB
    unsigned short* Bs = (unsigned short*)(smem_raw + 8192);   // 64x32 bf16 = 4 KB

    const int tid  = threadIdx.x;
    const int nwg  = gridDim.x;
    const int hw   = blockIdx.x;
    const int lg   = (hw & 7) * (nwg >> 3) + (hw >> 3);   // XCD-chunk swizzle
    const int bn   = (lg % nBlkN) * 64;
    const int bm   = (lg / nBlkN) * 128;
    const int wid  = tid >> 6;
    const int lane = tid & 63;
    const int wm   = (wid >> 1) * 64;
    const int wn   = (wid & 1) * 32;
    const int lr   = lane & 15;
    const int kc   = (lane >> 4) * 8;
    const int q4   = (lane >> 4) * 4;
    const int KP   = nT * 32;

    f32x4 acc[4][2];
    #pragma unroll
    for (int mi = 0; mi < 4; ++mi)
        #pragma unroll
        for (int ni = 0; ni < 2; ++ni) acc[mi][ni] = (f32x4){0.f, 0.f, 0.f, 0.f};

    for (int t = 0; t < nT; ++t) {
        const int k0 = t * 32;
        {
            const int n = tid >> 2, k8 = (tid & 3) * 8;
            gload_lds16(B + (size_t)(bn + n) * KP + k0 + k8,
                        (char*)Bs + tid * 16);
        }
        #pragma unroll
        for (int q = 0; q < 2; ++q) {
            const int idx = q * 256 + tid;
            const int m = idx >> 2, k8 = (idx & 3) * 8;
            gload_lds16(A + (size_t)(bm + m) * lda + k0 + k8,
                        (char*)As + idx * 16);
        }
        __syncthreads();

        bf16x8 a[4], bfr[2];
        #pragma unroll
        for (int mi = 0; mi < 4; ++mi)
            a[mi] = *(const bf16x8*)&As[(wm + mi * 16 + lr) * 32 + kc];
        #pragma unroll
        for (int ni = 0; ni < 2; ++ni)
            bfr[ni] = *(const bf16x8*)&Bs[(wn + ni * 16 + lr) * 32 + kc];
        #pragma unroll
        for (int mi = 0; mi < 4; ++mi)
            #pragma unroll
            for (int ni = 0; ni < 2; ++ni)
                acc[mi][ni] = __builtin_amdgcn_mfma_f32_16x16x32_bf16(
                    a[mi], bfr[ni], acc[mi][ni], 0, 0, 0);
        __syncthreads();
    }

    // ---- staged coalesced epilogue ----
    float gv[2], bv[2], ev[2];
    #pragma unroll
    for (int ni = 0; ni < 2; ++ni) {
        const int n = bn + wn + ni * 16 + lr;
        const bool nv = (n < Nreal);
        gv[ni] = nv ? gam[n]  : 0.f;
        bv[ni] = nv ? bias[n] : 0.f;
        ev[ni] = nv ? bet[n]  : 0.f;
    }

    if (CBF16) {
        __bf16* Cb = (__bf16*)smem_raw;               // [64][72] padded
        #pragma unroll
        for (int half = 0; half < 2; ++half) {
            if ((wm >> 6) == half) {
                #pragma unroll
                for (int ni = 0; ni < 2; ++ni) {
                    const int nl = wn + ni * 16 + lr;
                    #pragma unroll
                    for (int mi = 0; mi < 4; ++mi) {
                        #pragma unroll
                        for (int r = 0; r < 4; ++r) {
                            float v = gv[ni] * (acc[mi][ni][r] + bv[ni]) + ev[ni];
                            if (RELU) v = fmaxf(v, 0.f);
                            Cb[(mi * 16 + q4 + r) * 72 + nl] = (__bf16)v;
                        }
                    }
                }
            }
            __syncthreads();
            #pragma unroll
            for (int q = 0; q < 2; ++q) {
                const int idx = q * 256 + tid;
                const int row = idx >> 3, c16 = (idx & 7) * 8;
                const size_t m = (size_t)bm + half * 64 + row;
                *(bf16x8*)&((__bf16*)Cv)[m * ldc + bn + c16] =
                    *(const bf16x8*)&Cb[row * 72 + c16];
            }
            __syncthreads();
        }
    } else {
        float* Cf = (float*)smem_raw;                 // [32][68] padded
        const int ncols = (Nreal - bn < 64) ? (Nreal - bn) : 64;
        const int nch = ncols >> 2;
        #pragma unroll
        for (int mq = 0; mq < 4; ++mq) {
            if ((wm >> 6) == (mq >> 1)) {
                const int mi0 = (mq & 1) * 2;
                #pragma unroll
                for (int ni = 0; ni < 2; ++ni) {
                    const int nl = wn + ni * 16 + lr;
                    #pragma unroll
                    for (int mi2 = 0; mi2 < 2; ++mi2) {
                        const int mi = mi0 + mi2;
                        #pragma unroll
                        for (int r = 0; r < 4; ++r) {
                            float v = gv[ni] * (acc[mi][ni][r] + bv[ni]) + ev[ni];
                            if (RELU) v = fmaxf(v, 0.f);
                            Cf[(mi2 * 16 + q4 + r) * 68 + nl] = v;
                        }
                    }
                }
            }
            __syncthreads();
            for (int idx = tid; idx < 32 * nch; idx += 256) {
                const int row = idx / nch, c4 = (idx - row * nch) * 4;
                const size_t m = (size_t)bm + mq * 32 + row;
                *(float4*)&((float*)Cv)[m * ldc + bn + c4] =
                    *(const float4*)&Cf[row * 68 + c4];
            }
            __syncthreads();
        }
    }
}

// ---------------------------------------------------------------------------
extern "C" void kernel_launch(void* const* d_in, const int* in_sizes, int n_in,
                              void* d_out, int out_size, void* d_ws, size_t ws_size,
                              hipStream_t stream)
{
    const int*   order_p       = (const int*)d_in[0];
    const int*   x_atom        = (const int*)d_in[1];
    const int*   edge_index    = (const int*)d_in[2];
    const int*   edge_attr     = (const int*)d_in[3];
    const float* atom_tab      = (const float*)d_in[4];
    const float* bond_tab_root = (const float*)d_in[5];
    const float* edge_lin_w    = (const float*)d_in[6];
    const float* edge_lin_b    = (const float*)d_in[7];
    const float* bond_tabs     = (const float*)d_in[8];
    const float* eps           = (const float*)d_in[9];
    const float* w1            = (const float*)d_in[10];
    const float* b1            = (const float*)d_in[11];
    const float* bn1g          = (const float*)d_in[12];
    const float* bn1b          = (const float*)d_in[13];
    const float* w2            = (const float*)d_in[14];
    const float* b2            = (const float*)d_in[15];
    const float* bng           = (const float*)d_in[16];
    const float* bnb           = (const float*)d_in[17];

    float*  h  = (float*)d_out;    // final fp32 output [65536][300]
    __bf16* hb = (__bf16*)d_out;   // inter-layer trunk bf16 [65536][320]

    char* ws = (char*)d_ws;
    __bf16* Ahi_g = (__bf16*)ws;                                  // (inside z1)
    __bf16* Alo_g = (__bf16*)(ws + 17825792);                     // (inside z1)
    __bf16* z1    = (__bf16*)ws;                                  // [65536][640]
    __bf16* w1t   = (__bf16*)(ws + 83886080);                     // [5][640][320]
    __bf16* w2t   = (__bf16*)(ws + 83886080 + 2048000);           // [5][320][640]
    __bf16* zb    = (__bf16*)(ws + 83886080 + 4096000);           // [65536][320]
    int*    epk_s = (int*)(ws + 83886080 + 4096000 + 41943040);   // [512][512]
    int*    off_g = (int*)(ws + 83886080 + 4096000 + 41943040 + 1048576); // [512][129]
    __bf16* btb   = (__bf16*)(ws + 83886080 + 4096000 + 41943040 + 1048576 + 264192); // [5][192][300] = 576,000 B

    prep_w_kernel<<<17200, 256, 0, stream>>>(w1, w2, bond_tabs, w1t, w2t, btb);

    csr_kernel<<<NGRAPH, 128, 0, stream>>>(edge_index, edge_attr, epk_s, off_g);

    adj_kernel<<<NGRAPH, 512, 0, stream>>>(edge_index, edge_attr, bond_tab_root,
                                           edge_lin_w, edge_lin_b, Ahi_g, Alo_g);

    diffuse_mm_kernel<<<NGRAPH, 1024, 0, stream>>>(order_p, x_atom, atom_tab,
                                                   Ahi_g, Alo_g, hb);

    for (int l = 0; l < NLAYER; ++l) {
        agg_kernel<<<NGRAPH * 2, 1024, 0, stream>>>(
            hb, epk_s, off_g, btb, eps, l, zb);

        // gemm1: z1 = relu(bn1(zb @ w1 + b1))
        gemm_mfma<1, 1><<<5120, 256, 0, stream>>>(
            zb, 320, 10, 10, w1t + (size_t)l * 640 * 320,
            z1, 640, 600, b1 + l * 600, bn1g + l * 600, bn1b + l * 600);

        // gemm2: trunk = bn(z1 @ w2 + b2); bf16 hb for l<4, fp32 d_out for last
        if (l < NLAYER - 1) {
            gemm_mfma<1, 1><<<2560, 256, 0, stream>>>(
                z1, 640, 20, 5, w2t + (size_t)l * 320 * 640,
                hb, 320, 300, b2 + l * 300, bng + l * 300, bnb + l * 300);
        } else {
            gemm_mfma<0, 0><<<2560, 256, 0, stream>>>(
                z1, 640, 20, 5, w2t + (size_t)l * 320 * 640,
                h, EMB, 300, b2 + l * 300, bng + l * 300, bnb + l * 300);
        }
    }
}

// Round 17
// 1058.028 us; speedup vs baseline: 1.5471x; 1.0149x over previous
//
#include <hip/hip_runtime.h>

#define NGRAPH 512
#define NNODE  128
#define NEDGE  512
#define EMB    300
#define NLAYER 5
#define FA     9
#define FB     3
#define VV     64
#define KPAD   136   // padded K stride (bf16 elems) for A / xT tiles

typedef __bf16 bf16x8 __attribute__((ext_vector_type(8)));
typedef __bf16 bf16x4 __attribute__((ext_vector_type(4)));
typedef float  f32x4  __attribute__((ext_vector_type(4)));

__device__ __forceinline__ void gload_lds16(const void* gptr, void* lptr) {
    __builtin_amdgcn_global_load_lds(
        (const __attribute__((address_space(1))) void*)gptr,
        (__attribute__((address_space(3))) void*)lptr, 16, 0, 0);
}

// ---------------------------------------------------------------------------
// Kernel 0: weight prep — transpose w1/w2 to bf16 [N][K] (padded, zeros).
// (round-14 exact)
// ---------------------------------------------------------------------------
__global__ __launch_bounds__(256)
void prep_w_kernel(const float* __restrict__ w1, const float* __restrict__ w2,
                   __bf16* __restrict__ w1t, __bf16* __restrict__ w2t)
{
    const int i = blockIdx.x * 256 + threadIdx.x;
    const int T1 = NLAYER * 640 * 320;
    const int T2 = NLAYER * 320 * 640;
    if (i < T1) {
        const int l = i / (640 * 320);
        const int r = i - l * 640 * 320;
        const int n = r / 320, k = r - n * 320;
        float v = (n < 600 && k < 300) ? w1[((size_t)l * 300 + k) * 600 + n] : 0.f;
        w1t[i] = (__bf16)v;
    } else if (i < T1 + T2) {
        const int j = i - T1;
        const int l = j / (320 * 640);
        const int r = j - l * 320 * 640;
        const int n = r / 640, k = r - n * 640;
        float v = (n < 300 && k < 600) ? w2[((size_t)l * 600 + k) * 300 + n] : 0.f;
        w2t[j] = (__bf16)v;
    }
}

// ---------------------------------------------------------------------------
// Kernel 0b: one-shot CSR precompute (unchanged).
// ---------------------------------------------------------------------------
__global__ __launch_bounds__(128)
void csr_kernel(const int* __restrict__ edge_index,
                const int* __restrict__ edge_attr,
                int* __restrict__ epk_sorted,     // [G][512]
                int* __restrict__ off_g)          // [G][129]
{
    __shared__ int epk_s[NEDGE];
    __shared__ int cnt[128];
    __shared__ int off_[129];

    const int tid = threadIdx.x;
    const int g   = blockIdx.x;

    cnt[tid] = 0;
    __syncthreads();
    for (int e = tid; e < NEDGE; e += 128) {
        const int s_ = edge_index[(g * 2 + 0) * NEDGE + e];
        const int d_ = edge_index[(g * 2 + 1) * NEDGE + e];
        const int base = (g * NEDGE + e) * 3;
        epk_s[e] = s_ | (d_ << 7) | (edge_attr[base + 0] << 14)
                 | (edge_attr[base + 1] << 20) | (edge_attr[base + 2] << 26);
        atomicAdd(&cnt[d_], 1);
    }
    __syncthreads();
    if (tid < 64) {
        const int a = cnt[tid];
        const int b = cnt[64 + tid];
        int ia = a;
        #pragma unroll
        for (int o = 1; o < 64; o <<= 1) {
            int t = __shfl_up(ia, o, 64);
            if (tid >= o) ia += t;
        }
        const int totA = __shfl(ia, 63, 64);
        int ib = b;
        #pragma unroll
        for (int o = 1; o < 64; o <<= 1) {
            int t = __shfl_up(ib, o, 64);
            if (tid >= o) ib += t;
        }
        off_[tid]      = ia - a;
        off_[64 + tid] = totA + ib - b;
        if (tid == 63) off_[128] = totA + ib;
    }
    __syncthreads();
    off_g[g * 129 + tid] = off_[tid];
    if (tid == 0) off_g[g * 129 + 128] = off_[128];
    int pos = off_[tid];
    for (int e = 0; e < NEDGE; ++e) {
        const int p = epk_s[e];
        if (((p >> 7) & 127) == tid) epk_sorted[(g << 9) + pos++] = p;
    }
}

// ---------------------------------------------------------------------------
// Kernel 1a: adjacency build (round-14 exact).
// ---------------------------------------------------------------------------
__global__ __launch_bounds__(512)
void adj_kernel(const int* __restrict__ edge_index,
                const int* __restrict__ edge_attr,
                const float* __restrict__ bond_tab_root,
                const float* __restrict__ edge_lin_w,
                const float* __restrict__ edge_lin_b,
                __bf16* __restrict__ Ahi_g, __bf16* __restrict__ Alo_g)
{
    __shared__ float A[128 * 129];
    __shared__ float ew_s[NEDGE];
    __shared__ int   es[NEDGE];
    __shared__ float rinv[128];
    __shared__ float cinv[128];

    const int tid = threadIdx.x;
    const int g   = blockIdx.x;
    int* Ai = (int*)A;

    for (int e = tid; e < NEDGE; e += 512) {
        int r = edge_index[(g * 2 + 0) * NEDGE + e];
        int c = edge_index[(g * 2 + 1) * NEDGE + e];
        es[e] = r | (c << 8);
    }
    for (int i = tid; i < 128 * 129; i += 512) Ai[i] = -1;
    __syncthreads();

    {
        const int wave = tid >> 6, lane = tid & 63;
        const int sub = lane >> 3, sl = lane & 7;
        const float elb = edge_lin_b[0];
        #pragma unroll 2
        for (int it = 0; it < 8; ++it) {
            const int e = wave * 64 + it * 8 + sub;
            const int base = (g * NEDGE + e) * 3;
            const int a0 = edge_attr[base + 0];
            const int a1 = edge_attr[base + 1];
            const int a2 = edge_attr[base + 2];
            const float* t0 = bond_tab_root + (0 * VV + a0) * EMB;
            const float* t1 = bond_tab_root + (1 * VV + a1) * EMB;
            const float* t2 = bond_tab_root + (2 * VV + a2) * EMB;
            float acc = 0.f;
            for (int d = sl; d < EMB; d += 8)
                acc += (t0[d] + t1[d] + t2[d]) * edge_lin_w[d];
            acc += __shfl_xor(acc, 4, 64);
            acc += __shfl_xor(acc, 2, 64);
            acc += __shfl_xor(acc, 1, 64);
            if (sl == 0) ew_s[e] = 1.f / (1.f + expf(-(acc + elb)));
        }
    }
    for (int e = tid; e < NEDGE; e += 512) {
        int r = es[e] & 255, c = es[e] >> 8;
        atomicMax(&Ai[r * 129 + c], e);
        atomicMax(&Ai[c * 129 + r], 512 + e);
    }
    __syncthreads();
    for (int i = tid; i < 128 * 129; i += 512) {
        int p = Ai[i];
        A[i] = (p < 0) ? 0.f : ew_s[p & 511];
    }
    __syncthreads();
    if (tid < 128) A[tid * 129 + tid] += 1.f;
    __syncthreads();
    if (tid < 128) {
        float rs = 0.f, cs = 0.f;
        for (int j = 0; j < 128; ++j) { rs += A[tid * 129 + j]; cs += A[j * 129 + tid]; }
        rinv[tid] = 1.f / sqrtf(rs);
        cinv[tid] = 1.f / sqrtf(cs);
    }
    __syncthreads();
    for (int i = tid; i < 128 * KPAD; i += 512) {
        const int m = i / KPAD, k = i - m * KPAD;
        float v = (k < 128) ? A[m * 129 + k] * cinv[m] * rinv[k] : 0.f;
        __bf16 hi = (__bf16)v;
        Ahi_g[(size_t)g * 128 * KPAD + i] = hi;
        Alo_g[(size_t)g * 128 * KPAD + i] = (__bf16)(v - (float)hi);
    }
}

// ---------------------------------------------------------------------------
// Kernel 1b: diffusion via MFMA, TWO dim-chunks concurrent.
// 16 waves = 2 groups of 8; group cs owns chunk cb*2+cs (chunk 5..= idle).
// Per wave: 32 rows x 32 dims (2x2 frags). Phases drop 20 -> 12.
// Math identical to round 14 (A split hi/lo, x bf16 per hop).
// ---------------------------------------------------------------------------
__global__ __launch_bounds__(1024)
void diffuse_mm_kernel(const int* __restrict__ order_p,
                       const int* __restrict__ x_atom,
                       const float* __restrict__ atom_tab,
                       const __bf16* __restrict__ Ahi_g,
                       const __bf16* __restrict__ Alo_g,
                       __bf16* __restrict__ hb)
{
    __shared__ __bf16 Ahi[128 * KPAD];        // 34,816 B
    __shared__ __bf16 Alo[128 * KPAD];        // 34,816 B
    __shared__ __bf16 xt[4 * 64 * KPAD];      // 69,632 B: [cs*2+buf][n][m]
    __shared__ int    xat[128 * FA];          // 4,608 B   (total 143,872)

    const int tid  = threadIdx.x;
    const int g    = blockIdx.x;
    const int lane = tid & 63;
    const int wid  = tid >> 6;            // 0..15
    const int cs   = wid >> 3;            // chunk-group 0/1
    const int w8   = wid & 7;             // 0..7 within group
    const int wm   = (w8 >> 1) * 32;      // 0,32,64,96
    const int wn   = (w8 & 1) * 32;       // 0,32
    const int lr   = lane & 15;
    const int q4   = (lane >> 4) * 4;
    const int kc   = (lane >> 4) * 8;

    for (int idx = tid; idx < 128 * KPAD / 8; idx += 1024) {
        gload_lds16(Ahi_g + (size_t)g * 128 * KPAD + idx * 8, (char*)Ahi + idx * 16);
        gload_lds16(Alo_g + (size_t)g * 128 * KPAD + idx * 8, (char*)Alo + idx * 16);
    }
    for (int i = tid; i < 128 * FA; i += 1024) xat[i] = x_atom[g * 128 * FA + i];
    __syncthreads();

    const int   ord    = order_p[0];
    const float yscale = 1.f / (float)(ord + 1);

    for (int cb = 0; cb < 3; ++cb) {
        const int  chunk = cb * 2 + cs;
        const bool valid = (chunk < 5);
        const int  dbase = chunk * 64;

        // ---- encode chunk in fp32 -> bf16 xt buf0, seed y ----
        float yacc[2][2][4];
        #pragma unroll
        for (int mi = 0; mi < 2; ++mi) {
            #pragma unroll
            for (int ni = 0; ni < 2; ++ni) {
                const int n_ = wn + ni * 16 + lr;
                const int d  = dbase + n_;
                #pragma unroll
                for (int r = 0; r < 4; ++r) {
                    const int m_ = wm + mi * 16 + q4 + r;
                    float v = 0.f;
                    if (valid && d < EMB) {
                        #pragma unroll
                        for (int f = 0; f < FA; ++f)
                            v += atom_tab[(size_t)((f << 6) + xat[m_ * FA + f]) * EMB + d];
                        v *= 0.8f;
                    }
                    yacc[mi][ni][r] = v;
                    xt[(cs * 2 + 0) * 64 * KPAD + n_ * KPAD + m_] = (__bf16)v;
                }
            }
        }
        __syncthreads();

        int curbuf = 0;
        for (int o = 0; o < ord; ++o) {
            const __bf16* xh = xt + (cs * 2 + curbuf) * 64 * KPAD;
            f32x4 racc[2][2];
            #pragma unroll
            for (int mi = 0; mi < 2; ++mi)
                #pragma unroll
                for (int ni = 0; ni < 2; ++ni) racc[mi][ni] = (f32x4){0.f, 0.f, 0.f, 0.f};

            #pragma unroll
            for (int ks = 0; ks < 4; ++ks) {
                const int k0 = ks * 32 + kc;
                bf16x8 ah[2], al[2], bh[2];
                #pragma unroll
                for (int mi = 0; mi < 2; ++mi) {
                    ah[mi] = *(const bf16x8*)&Ahi[(wm + mi * 16 + lr) * KPAD + k0];
                    al[mi] = *(const bf16x8*)&Alo[(wm + mi * 16 + lr) * KPAD + k0];
                }
                #pragma unroll
                for (int ni = 0; ni < 2; ++ni)
                    bh[ni] = *(const bf16x8*)&xh[(wn + ni * 16 + lr) * KPAD + k0];
                #pragma unroll
                for (int mi = 0; mi < 2; ++mi) {
                    #pragma unroll
                    for (int ni = 0; ni < 2; ++ni) {
                        racc[mi][ni] = __builtin_amdgcn_mfma_f32_16x16x32_bf16(
                            ah[mi], bh[ni], racc[mi][ni], 0, 0, 0);
                        racc[mi][ni] = __builtin_amdgcn_mfma_f32_16x16x32_bf16(
                            al[mi], bh[ni], racc[mi][ni], 0, 0, 0);
                    }
                }
            }

            __bf16* nh = xt + (cs * 2 + (curbuf ^ 1)) * 64 * KPAD;
            #pragma unroll
            for (int mi = 0; mi < 2; ++mi) {
                #pragma unroll
                for (int ni = 0; ni < 2; ++ni) {
                    const int n_ = wn + ni * 16 + lr;
                    const int mbase = wm + mi * 16 + q4;
                    bf16x4 hv;
                    #pragma unroll
                    for (int r = 0; r < 4; ++r) {
                        const float v = racc[mi][ni][r];
                        yacc[mi][ni][r] += v;
                        hv[r] = (__bf16)v;
                    }
                    *(bf16x4*)&nh[n_ * KPAD + mbase] = hv;
                }
            }
            __syncthreads();
            curbuf ^= 1;
        }

        // hb write: bf16, stride 320, pad (d>=300) zeroed
        if (valid) {
            #pragma unroll
            for (int mi = 0; mi < 2; ++mi) {
                #pragma unroll
                for (int ni = 0; ni < 2; ++ni) {
                    const int n_ = wn + ni * 16 + lr;
                    const int d  = dbase + n_;
                    #pragma unroll
                    for (int r = 0; r < 4; ++r) {
                        const int m_ = wm + mi * 16 + q4 + r;
                        const float v = (d < EMB) ? yacc[mi][ni][r] * yscale : 0.f;
                        hb[(size_t)(g * 128 + m_) * 320 + d] = (__bf16)v;
                    }
                }
            }
        }
    }
}

// ---------------------------------------------------------------------------
// Kernel 2: GIN aggregation, CSR gather, DUAL-NODE interleave for 2x MLP.
// fp32 bond tables (r14 numerics); per-node accumulation order unchanged.
// ---------------------------------------------------------------------------
__global__ __launch_bounds__(1024)
void agg_kernel(const __bf16* __restrict__ hb,
                const int* __restrict__ epk_sorted,
                const int* __restrict__ off_g,
                const float* __restrict__ bond_tabs,
                const float* __restrict__ eps_all,
                const int l,
                __bf16* __restrict__ zb)
{
    __shared__ __bf16 hs[128 * 160];

    const int tid  = threadIdx.x;
    const int g    = blockIdx.x >> 1;
    const int coff = (blockIdx.x & 1) * 160;
    const int wave = tid >> 6, lane = tid & 63;
    const float epl = 1.f + eps_all[l];
    const float* bt = bond_tabs + (size_t)l * FB * VV * EMB;

    for (int idx = tid; idx < 128 * 20; idx += 1024) {
        const int r = idx / 20, c = idx - r * 20;
        *(bf16x8*)&hs[r * 160 + c * 8] =
            *(const bf16x8*)&hb[(size_t)(g * 128 + r) * 320 + coff + c * 8];
    }
    __syncthreads();

    const int d0 = lane, d1 = lane + 64, d2 = lane + 128;
    const bool r0 = (coff + d0) < EMB;
    const bool r1 = (coff + d1) < EMB;
    const bool r2 = (d2 < 160) && ((coff + d2) < EMB);

    const int* offg = off_g + g * 129;
    const int* epkg = epk_sorted + (g << 9);

    for (int nb = wave; nb < 64; nb += 16) {
        const int n0 = nb, n1 = nb + 64;
        float a0 = r0 ? epl * (float)hs[n0 * 160 + d0] : 0.f;
        float a1 = r1 ? epl * (float)hs[n0 * 160 + d1] : 0.f;
        float a2 = r2 ? epl * (float)hs[n0 * 160 + d2] : 0.f;
        float b0 = r0 ? epl * (float)hs[n1 * 160 + d0] : 0.f;
        float b1 = r1 ? epl * (float)hs[n1 * 160 + d1] : 0.f;
        float b2 = r2 ? epl * (float)hs[n1 * 160 + d2] : 0.f;
        int eA = offg[n0];
        int eB = offg[n1];
        const int eAe = offg[n0 + 1];
        const int eBe = offg[n1 + 1];

        while (eA < eAe && eB < eBe) {
            {
                const int p   = epkg[eA++];
                const int src = p & 127;
                const float* t0 = bt + ((p >> 14) & 63) * EMB + coff;
                const float* t1 = bt + (64  + ((p >> 20) & 63)) * EMB + coff;
                const float* t2 = bt + (128 + ((p >> 26) & 63)) * EMB + coff;
                if (r0) a0 += fmaxf((float)hs[src * 160 + d0] + t0[d0] + t1[d0] + t2[d0], 0.f);
                if (r1) a1 += fmaxf((float)hs[src * 160 + d1] + t0[d1] + t1[d1] + t2[d1], 0.f);
                if (r2) a2 += fmaxf((float)hs[src * 160 + d2] + t0[d2] + t1[d2] + t2[d2], 0.f);
            }
            {
                const int p   = epkg[eB++];
                const int src = p & 127;
                const float* t0 = bt + ((p >> 14) & 63) * EMB + coff;
                const float* t1 = bt + (64  + ((p >> 20) & 63)) * EMB + coff;
                const float* t2 = bt + (128 + ((p >> 26) & 63)) * EMB + coff;
                if (r0) b0 += fmaxf((float)hs[src * 160 + d0] + t0[d0] + t1[d0] + t2[d0], 0.f);
                if (r1) b1 += fmaxf((float)hs[src * 160 + d1] + t0[d1] + t1[d1] + t2[d1], 0.f);
                if (r2) b2 += fmaxf((float)hs[src * 160 + d2] + t0[d2] + t1[d2] + t2[d2], 0.f);
            }
        }
        while (eA < eAe) {
            const int p   = epkg[eA++];
            const int src = p & 127;
            const float* t0 = bt + ((p >> 14) & 63) * EMB + coff;
            const float* t1 = bt + (64  + ((p >> 20) & 63)) * EMB + coff;
            const float* t2 = bt + (128 + ((p >> 26) & 63)) * EMB + coff;
            if (r0) a0 += fmaxf((float)hs[src * 160 + d0] + t0[d0] + t1[d0] + t2[d0], 0.f);
            if (r1) a1 += fmaxf((float)hs[src * 160 + d1] + t0[d1] + t1[d1] + t2[d1], 0.f);
            if (r2) a2 += fmaxf((float)hs[src * 160 + d2] + t0[d2] + t1[d2] + t2[d2], 0.f);
        }
        while (eB < eBe) {
            const int p   = epkg[eB++];
            const int src = p & 127;
            const float* t0 = bt + ((p >> 14) & 63) * EMB + coff;
            const float* t1 = bt + (64  + ((p >> 20) & 63)) * EMB + coff;
            const float* t2 = bt + (128 + ((p >> 26) & 63)) * EMB + coff;
            if (r0) b0 += fmaxf((float)hs[src * 160 + d0] + t0[d0] + t1[d0] + t2[d0], 0.f);
            if (r1) b1 += fmaxf((float)hs[src * 160 + d1] + t0[d1] + t1[d1] + t2[d1], 0.f);
            if (r2) b2 += fmaxf((float)hs[src * 160 + d2] + t0[d2] + t1[d2] + t2[d2], 0.f);
        }

        __bf16* zr0 = zb + (size_t)(g * 128 + n0) * 320 + coff;
        __bf16* zr1 = zb + (size_t)(g * 128 + n1) * 320 + coff;
        zr0[d0] = (__bf16)a0;
        zr0[d1] = (__bf16)a1;
        if (d2 < 160) zr0[d2] = (__bf16)a2;
        zr1[d0] = (__bf16)b0;
        zr1[d1] = (__bf16)b1;
        if (d2 < 160) zr1[d2] = (__bf16)b2;
    }
}

// ---------------------------------------------------------------------------
// Kernel 3: bf16 MFMA GEMM with XCD-chunk swizzle + LDS-staged coalesced
// epilogue (round-14 exact).
// ---------------------------------------------------------------------------
template <int CBF16, int RELU>
__global__ __launch_bounds__(256)
void gemm_mfma(const __bf16* __restrict__ A, const int lda,
               const int nT, const int nBlkN, const __bf16* __restrict__ B,
               void* __restrict__ Cv, const int ldc, const int Nreal,
               const float* __restrict__ bias, const float* __restrict__ gam,
               const float* __restrict__ bet)
{
    __shared__ __align__(16) char smem_raw[12288];
    unsigned short* As = (unsigned short*)smem_raw;            // 128x32 bf16 = 8 KB
    unsigned short* Bs = (unsigned short*)(smem_raw + 8192);   // 64x32 bf16 = 4 KB

    const int tid  = threadIdx.x;
    const int nwg  = gridDim.x;
    const int hw   = blockIdx.x;
    const int lg   = (hw & 7) * (nwg >> 3) + (hw >> 3);   // XCD-chunk swizzle
    const int bn   = (lg % nBlkN) * 64;
    const int bm   = (lg / nBlkN) * 128;
    const int wid  = tid >> 6;
    const int lane = tid & 63;
    const int wm   = (wid >> 1) * 64;
    const int wn   = (wid & 1) * 32;
    const int lr   = lane & 15;
    const int kc   = (lane >> 4) * 8;
    const int q4   = (lane >> 4) * 4;
    const int KP   = nT * 32;

    f32x4 acc[4][2];
    #pragma unroll
    for (int mi = 0; mi < 4; ++mi)
        #pragma unroll
        for (int ni = 0; ni < 2; ++ni) acc[mi][ni] = (f32x4){0.f, 0.f, 0.f, 0.f};

    for (int t = 0; t < nT; ++t) {
        const int k0 = t * 32;
        {
            const int n = tid >> 2, k8 = (tid & 3) * 8;
            gload_lds16(B + (size_t)(bn + n) * KP + k0 + k8,
                        (char*)Bs + tid * 16);
        }
        #pragma unroll
        for (int q = 0; q < 2; ++q) {
            const int idx = q * 256 + tid;
            const int m = idx >> 2, k8 = (idx & 3) * 8;
            gload_lds16(A + (size_t)(bm + m) * lda + k0 + k8,
                        (char*)As + idx * 16);
        }
        __syncthreads();

        bf16x8 a[4], bfr[2];
        #pragma unroll
        for (int mi = 0; mi < 4; ++mi)
            a[mi] = *(const bf16x8*)&As[(wm + mi * 16 + lr) * 32 + kc];
        #pragma unroll
        for (int ni = 0; ni < 2; ++ni)
            bfr[ni] = *(const bf16x8*)&Bs[(wn + ni * 16 + lr) * 32 + kc];
        #pragma unroll
        for (int mi = 0; mi < 4; ++mi)
            #pragma unroll
            for (int ni = 0; ni < 2; ++ni)
                acc[mi][ni] = __builtin_amdgcn_mfma_f32_16x16x32_bf16(
                    a[mi], bfr[ni], acc[mi][ni], 0, 0, 0);
        __syncthreads();
    }

    // ---- staged coalesced epilogue ----
    float gv[2], bv[2], ev[2];
    #pragma unroll
    for (int ni = 0; ni < 2; ++ni) {
        const int n = bn + wn + ni * 16 + lr;
        const bool nv = (n < Nreal);
        gv[ni] = nv ? gam[n]  : 0.f;
        bv[ni] = nv ? bias[n] : 0.f;
        ev[ni] = nv ? bet[n]  : 0.f;
    }

    if (CBF16) {
        __bf16* Cb = (__bf16*)smem_raw;               // [64][72] padded
        #pragma unroll
        for (int half = 0; half < 2; ++half) {
            if ((wm >> 6) == half) {
                #pragma unroll
                for (int ni = 0; ni < 2; ++ni) {
                    const int nl = wn + ni * 16 + lr;
                    #pragma unroll
                    for (int mi = 0; mi < 4; ++mi) {
                        #pragma unroll
                        for (int r = 0; r < 4; ++r) {
                            float v = gv[ni] * (acc[mi][ni][r] + bv[ni]) + ev[ni];
                            if (RELU) v = fmaxf(v, 0.f);
                            Cb[(mi * 16 + q4 + r) * 72 + nl] = (__bf16)v;
                        }
                    }
                }
            }
            __syncthreads();
            #pragma unroll
            for (int q = 0; q < 2; ++q) {
                const int idx = q * 256 + tid;
                const int row = idx >> 3, c16 = (idx & 7) * 8;
                const size_t m = (size_t)bm + half * 64 + row;
                *(bf16x8*)&((__bf16*)Cv)[m * ldc + bn + c16] =
                    *(const bf16x8*)&Cb[row * 72 + c16];
            }
            __syncthreads();
        }
    } else {
        float* Cf = (float*)smem_raw;                 // [32][68] padded
        const int ncols = (Nreal - bn < 64) ? (Nreal - bn) : 64;
        const int nch = ncols >> 2;
        #pragma unroll
        for (int mq = 0; mq < 4; ++mq) {
            if ((wm >> 6) == (mq >> 1)) {
                const int mi0 = (mq & 1) * 2;
                #pragma unroll
                for (int ni = 0; ni < 2; ++ni) {
                    const int nl = wn + ni * 16 + lr;
                    #pragma unroll
                    for (int mi2 = 0; mi2 < 2; ++mi2) {
                        const int mi = mi0 + mi2;
                        #pragma unroll
                        for (int r = 0; r < 4; ++r) {
                            float v = gv[ni] * (acc[mi][ni][r] + bv[ni]) + ev[ni];
                            if (RELU) v = fmaxf(v, 0.f);
                            Cf[(mi2 * 16 + q4 + r) * 68 + nl] = v;
                        }
                    }
                }
            }
            __syncthreads();
            for (int idx = tid; idx < 32 * nch; idx += 256) {
                const int row = idx / nch, c4 = (idx - row * nch) * 4;
                const size_t m = (size_t)bm + mq * 32 + row;
                *(float4*)&((float*)Cv)[m * ldc + bn + c4] =
                    *(const float4*)&Cf[row * 68 + c4];
            }
            __syncthreads();
        }
    }
}

// ---------------------------------------------------------------------------
extern "C" void kernel_launch(void* const* d_in, const int* in_sizes, int n_in,
                              void* d_out, int out_size, void* d_ws, size_t ws_size,
                              hipStream_t stream)
{
    const int*   order_p       = (const int*)d_in[0];
    const int*   x_atom        = (const int*)d_in[1];
    const int*   edge_index    = (const int*)d_in[2];
    const int*   edge_attr     = (const int*)d_in[3];
    const float* atom_tab      = (const float*)d_in[4];
    const float* bond_tab_root = (const float*)d_in[5];
    const float* edge_lin_w    = (const float*)d_in[6];
    const float* edge_lin_b    = (const float*)d_in[7];
    const float* bond_tabs     = (const float*)d_in[8];
    const float* eps           = (const float*)d_in[9];
    const float* w1            = (const float*)d_in[10];
    const float* b1            = (const float*)d_in[11];
    const float* bn1g          = (const float*)d_in[12];
    const float* bn1b          = (const float*)d_in[13];
    const float* w2            = (const float*)d_in[14];
    const float* b2            = (const float*)d_in[15];
    const float* bng           = (const float*)d_in[16];
    const float* bnb           = (const float*)d_in[17];

    float*  h  = (float*)d_out;    // final fp32 output [65536][300]
    __bf16* hb = (__bf16*)d_out;   // inter-layer trunk bf16 [65536][320]

    char* ws = (char*)d_ws;
    __bf16* Ahi_g = (__bf16*)ws;                                  // (inside z1)
    __bf16* Alo_g = (__bf16*)(ws + 17825792);                     // (inside z1)
    __bf16* z1    = (__bf16*)ws;                                  // [65536][640]
    __bf16* w1t   = (__bf16*)(ws + 83886080);                     // [5][640][320]
    __bf16* w2t   = (__bf16*)(ws + 83886080 + 2048000);           // [5][320][640]
    __bf16* zb    = (__bf16*)(ws + 83886080 + 4096000);           // [65536][320]
    int*    epk_s = (int*)(ws + 83886080 + 4096000 + 41943040);   // [512][512]
    int*    off_g = (int*)(ws + 83886080 + 4096000 + 41943040 + 1048576); // [512][129]

    prep_w_kernel<<<8000, 256, 0, stream>>>(w1, w2, w1t, w2t);

    csr_kernel<<<NGRAPH, 128, 0, stream>>>(edge_index, edge_attr, epk_s, off_g);

    adj_kernel<<<NGRAPH, 512, 0, stream>>>(edge_index, edge_attr, bond_tab_root,
                                           edge_lin_w, edge_lin_b, Ahi_g, Alo_g);

    diffuse_mm_kernel<<<NGRAPH, 1024, 0, stream>>>(order_p, x_atom, atom_tab,
                                                   Ahi_g, Alo_g, hb);

    for (int l = 0; l < NLAYER; ++l) {
        agg_kernel<<<NGRAPH * 2, 1024, 0, stream>>>(
            hb, epk_s, off_g, bond_tabs, eps, l, zb);

        // gemm1: z1 = relu(bn1(zb @ w1 + b1))
        gemm_mfma<1, 1><<<5120, 256, 0, stream>>>(
            zb, 320, 10, 10, w1t + (size_t)l * 640 * 320,
            z1, 640, 600, b1 + l * 600, bn1g + l * 600, bn1b + l * 600);

        // gemm2: trunk = bn(z1 @ w2 + b2); bf16 hb for l<4, fp32 d_out for last
        if (l < NLAYER - 1) {
            gemm_mfma<1, 1><<<2560, 256, 0, stream>>>(
                z1, 640, 20, 5, w2t + (size_t)l * 320 * 640,
                hb, 320, 300, b2 + l * 300, bng + l * 300, bnb + l * 300);
        } else {
            gemm_mfma<0, 0><<<2560, 256, 0, stream>>>(
                z1, 640, 20, 5, w2t + (size_t)l * 320 * 640,
                h, EMB, 300, b2 + l * 300, bng + l * 300, bnb + l * 300);
        }
    }
}